// Round 9
// baseline (70.727 us; speedup 1.0000x reference)
//
#include <hip/hip_runtime.h>

#define BT 256           // 4 waves per block
#define WREG 9216        // per-wave LDS: 64 rows x 144 B (A-area; ro-strip + V overlay it)
// A-row: 72 shorts = 48 bf16 obs + 16 zero K-pad (shorts 48..63; also gather sentinel)
// ro-strip (post-MFMA, per column-tile): words 0..15 of each row, reused 3x
// V-area (post-VI): words 0..15 + zero sentinel word 16

typedef __attribute__((ext_vector_type(8))) short short8;
typedef __attribute__((ext_vector_type(4))) float f32x4;
typedef __attribute__((ext_vector_type(4))) unsigned int u32x4;
typedef _Float16 h2 __attribute__((ext_vector_type(2)));

// pack two f32 -> two bf16 (RNE), single VOP3 instruction (no builtin on gfx950)
__device__ inline unsigned cvtpkbf(float a, float b) {
    unsigned d;
    asm("v_cvt_pk_bf16_f32 %0, %1, %2" : "=v"(d) : "v"(a), "v"(b));
    return d;
}
__device__ inline float b2f(short s) {
    unsigned u = ((unsigned)(unsigned short)s) << 16;
    return __builtin_bit_cast(float, u);
}
// pack two f32 -> two f16 (RTZ)
__device__ inline unsigned pkrtz(float a, float b) {
    unsigned d;
    asm("v_cvt_pkrtz_f16_f32 %0, %1, %2" : "=v"(d) : "v"(a), "v"(b));
    return d;
}
// packed f16 ops (VOP3P)
__device__ inline unsigned pkfma(unsigned a, unsigned b, unsigned c) {
    unsigned d;
    asm("v_pk_fma_f16 %0, %1, %2, %3" : "=v"(d) : "v"(a), "v"(b), "v"(c));
    return d;
}
__device__ inline unsigned pkmax(unsigned a, unsigned b) {
    unsigned d;
    asm("v_pk_max_f16 %0, %1, %2" : "=v"(d) : "v"(a), "v"(b));
    return d;
}
__device__ inline unsigned pksub(unsigned a, unsigned b) {   // a - b (both halves)
    unsigned d;
    asm("v_pk_add_f16 %0, %1, %2 neg_lo:[0,1] neg_hi:[0,1]" : "=v"(d) : "v"(a), "v"(b));
    return d;
}
__device__ inline unsigned pkneg(unsigned b) {               // 0 - b
    unsigned d;
    asm("v_pk_add_f16 %0, 0, %1 neg_lo:[0,1] neg_hi:[0,1]" : "=v"(d) : "v"(b));
    return d;
}

__global__ __launch_bounds__(BT, 4) void vin_kernel(
    const float* __restrict__ obs,
    const float* __restrict__ PhiW,
    const float* __restrict__ Phib,
    const float* __restrict__ LW,
    const float* __restrict__ Lb,
    float* __restrict__ out, int Btot)
{
    __shared__ __align__(16) char smem[4 * WREG];   // 36864 B -> 4 blocks/CU
    const int tid  = threadIdx.x;
    const int lane = tid & 63;
    const int wid  = tid >> 6;
    const int b    = blockIdx.x * BT + tid;
    // Btot % 64 == 0, waves entirely in or out; no barriers -> early return safe
    if (b >= Btot) return;

    char* wbase = smem + wid * WREG;
    const int jn = lane & 15;
    const int g  = lane >> 4;

    // ---- load obs row (48 f32, 12x float4, coalesced) ----
    float o[48];
    {
        const float4* g4 = reinterpret_cast<const float4*>(obs + (size_t)b * 48);
        #pragma unroll
        for (int q = 0; q < 12; ++q) {
            float4 t = g4[q];
            o[4*q+0] = t.x; o[4*q+1] = t.y; o[4*q+2] = t.z; o[4*q+3] = t.w;
        }
    }

    // ---- agent index: channel 1 is exactly one-hot (values exactly 1.0f) ----
    float ssum = o[1], sidx = 0.0f;
    #pragma unroll
    for (int k = 1; k < 16; ++k) {
        ssum += o[k*3 + 1];
        sidx = fmaf(o[k*3 + 1], (float)k, sidx);
    }
    const int idx = (ssum != 0.0f) ? (int)(sidx + 0.5f) : 5;
    const int ai = idx >> 2;
    const int aj = idx & 3;

    // ---- B-fragments: PhiW^T tiles straight from global (L2-hot), bf16 ----
    // B[k][j] = PhiW[j*48+k]; lane holds col j=16n+jn, k = 32t+8g..+7
    short8 bfrag[3][2];
    #pragma unroll
    for (int n = 0; n < 3; ++n) {
        const float* wrow = PhiW + (16*n + jn) * 48;
        float4 q0 = *reinterpret_cast<const float4*>(wrow + 8*g);
        float4 q1 = *reinterpret_cast<const float4*>(wrow + 8*g + 4);
        u32x4 t0;
        t0[0] = cvtpkbf(q0.x, q0.y); t0[1] = cvtpkbf(q0.z, q0.w);
        t0[2] = cvtpkbf(q1.x, q1.y); t0[3] = cvtpkbf(q1.z, q1.w);
        bfrag[n][0] = __builtin_bit_cast(short8, t0);
        u32x4 tz = {0u, 0u, 0u, 0u};
        if (g < 2) {   // k = 32+8g..+7 valid only for g<2; k>=48 zero pad
            float4 q2 = *reinterpret_cast<const float4*>(wrow + 32 + 8*g);
            float4 q3 = *reinterpret_cast<const float4*>(wrow + 36 + 8*g);
            tz[0] = cvtpkbf(q2.x, q2.y); tz[1] = cvtpkbf(q2.z, q2.w);
            tz[2] = cvtpkbf(q3.x, q3.y); tz[3] = cvtpkbf(q3.z, q3.w);
        }
        bfrag[n][1] = __builtin_bit_cast(short8, tz);
    }

    // ---- write own obs row to A-area as bf16 (packed cvt), K-pad to 64 ----
    {
        u32x4* arow = reinterpret_cast<u32x4*>(wbase + lane * 144);
        #pragma unroll
        for (int q = 0; q < 6; ++q) {
            u32x4 v;
            #pragma unroll
            for (int e = 0; e < 4; ++e)
                v[e] = cvtpkbf(o[q*8 + 2*e], o[q*8 + 2*e + 1]);
            arow[q] = v;
        }
        u32x4 z = {0u, 0u, 0u, 0u};
        arow[6] = z; arow[7] = z;   // shorts 48..63 zero (K-pad + gather sentinel)
    }

    // ---- sub_state gather (features 0..26) from own bf16 row ----
    // OOB windows read the zero-pad at shorts 48..50 (sentinel) - no value masks.
    float lg0 = Lb[0], lg1 = Lb[1], lg2 = Lb[2], lg3 = Lb[3];
    {
        const short* myobs = reinterpret_cast<const short*>(wbase + lane * 144);
        #pragma unroll
        for (int dh = 0; dh < 3; ++dh)
            #pragma unroll
            for (int dw = 0; dw < 3; ++dw) {
                int r = ai + dh - 1, c = aj + dw - 1;
                bool ok = ((unsigned)r < 4u) && ((unsigned)c < 4u);
                int ba = ok ? (r*4 + c) * 3 : 48;
                float s0 = b2f(myobs[ba+0]);
                float s1 = b2f(myobs[ba+1]);
                float s2 = b2f(myobs[ba+2]);
                int f = (dh*3 + dw) * 3;
                lg0 = fmaf(s0, LW[0*36+f], fmaf(s1, LW[0*36+f+1], fmaf(s2, LW[0*36+f+2], lg0)));
                lg1 = fmaf(s0, LW[1*36+f], fmaf(s1, LW[1*36+f+1], fmaf(s2, LW[1*36+f+2], lg1)));
                lg2 = fmaf(s0, LW[2*36+f], fmaf(s1, LW[2*36+f+1], fmaf(s2, LW[2*36+f+2], lg2)));
                lg3 = fmaf(s0, LW[3*36+f], fmaf(s1, LW[3*36+f+1], fmaf(s2, LW[3*36+f+2], lg3)));
            }
    }

    // ---- A-fragments: lane reads row m*16+jn, k = 32t+8g..+7 ----
    short8 afrag[4][2];
    #pragma unroll
    for (int m = 0; m < 4; ++m) {
        const char* rp = wbase + (m*16 + jn) * 144;
        afrag[m][0] = *reinterpret_cast<const short8*>(rp + 16*g);
        afrag[m][1] = *reinterpret_cast<const short8*>(rp + 64 + 16*g);
    }

    // ---- 24 MFMAs, bias folded into C-init (bias per col j=16n+jn) ----
    f32x4 acc[4][3];
    {
        float b0 = Phib[jn], b1 = Phib[16 + jn], b2 = Phib[32 + jn];
        #pragma unroll
        for (int m = 0; m < 4; ++m) {
            acc[m][0] = (f32x4){b0, b0, b0, b0};
            acc[m][1] = (f32x4){b1, b1, b1, b1};
            acc[m][2] = (f32x4){b2, b2, b2, b2};
        }
    }
    #pragma unroll
    for (int n = 0; n < 3; ++n)
        #pragma unroll
        for (int m = 0; m < 4; ++m) {
            acc[m][n] = __builtin_amdgcn_mfma_f32_16x16x32_bf16(afrag[m][0], bfrag[n][0], acc[m][n], 0, 0, 0);
            acc[m][n] = __builtin_amdgcn_mfma_f32_16x16x32_bf16(afrag[m][1], bfrag[n][1], acc[m][n], 0, 0, 0);
        }

    // A-area ds_reads complete before the strip overwrites the rows
    asm volatile("s_waitcnt lgkmcnt(0)" ::: "memory");
    __builtin_amdgcn_sched_barrier(0);

    // ---- 3-tile scatter/readback through the 64x16-word strip (overlays A) ----
    // tile n: lane scatters acc[m][n][r] to word jn of row m*16+g*4+r,
    // then reads back its own row's 16 f32 (cols 16n..16n+15) and routes them
    // to rin/rout/p staging by col%3.
    float rinf[16], routf[16], pcf[16];
    #pragma unroll
    for (int n = 0; n < 3; ++n) {
        #pragma unroll
        for (int m = 0; m < 4; ++m)
            #pragma unroll
            for (int r = 0; r < 4; ++r) {
                int row = m*16 + g*4 + r;
                reinterpret_cast<float*>(wbase + row * 144)[jn] = acc[m][n][r];
            }
        asm volatile("s_waitcnt lgkmcnt(0)" ::: "memory");
        __builtin_amdgcn_sched_barrier(0);
        const char* myrow = wbase + lane * 144;
        #pragma unroll
        for (int q = 0; q < 4; ++q) {
            f32x4 t = *reinterpret_cast<const f32x4*>(myrow + q * 16);
            #pragma unroll
            for (int e = 0; e < 4; ++e) {
                int c = 16*n + 4*q + e;
                int cell = c / 3, ch = c - 3*cell;
                if (ch == 0)      rinf[cell]  = t[e];
                else if (ch == 1) routf[cell] = t[e];
                else              pcf[cell]   = t[e];
            }
        }
        asm volatile("s_waitcnt lgkmcnt(0)" ::: "memory");
        __builtin_amdgcn_sched_barrier(0);
    }

    // ---- pack rin/rout/p into f16 pairs (cl, cl+2), build a* in packed math ----
    unsigned rinp[4][2], routp[4][2], pp[4][2];
    #pragma unroll
    for (int h = 0; h < 4; ++h)
        #pragma unroll
        for (int j = 0; j < 2; ++j) {
            int c0 = 4*h + j, c1 = 4*h + j + 2;
            rinp[h][j]  = pkrtz(rinf[c0], rinf[c1]);
            routp[h][j] = pkrtz(routf[c0], routf[c1]);
            pp[h][j]    = pkrtz(pcf[c0], pcf[c1]);
        }
    unsigned aL2[4][2], aR2[4][2], aU2[4][2], aD2[4][2];
    #pragma unroll
    for (int h = 0; h < 4; ++h) {
        aL2[h][0] = pksub(rinp[h][1] << 16, routp[h][0]);
        aL2[h][1] = pksub(rinp[h][0], routp[h][1]);
        aR2[h][0] = pksub(rinp[h][1], routp[h][0]);
        aR2[h][1] = pksub(rinp[h][0] >> 16, routp[h][1]);
        #pragma unroll
        for (int j = 0; j < 2; ++j) {
            aU2[h][j] = (h > 0) ? pksub(rinp[h-1][j], routp[h][j]) : pkneg(routp[0][j]);
            aD2[h][j] = (h < 3) ? pksub(rinp[h+1][j], routp[h][j]) : pkneg(routp[3][j]);
        }
    }

    // ---- K=20 VI steps, packed f16 (pack (h,j): lo=V[h][j], hi=V[h][j+2]) ----
    unsigned Vp[4][2];
    #pragma unroll
    for (int h = 0; h < 4; ++h) { Vp[h][0] = 0u; Vp[h][1] = 0u; }

    #pragma unroll 1
    for (int s = 0; s < 20; ++s) {
        unsigned shl[4], shr[4], Vn[4][2];
        #pragma unroll
        for (int h = 0; h < 4; ++h) {
            shl[h] = Vp[h][1] << 16;
            shr[h] = Vp[h][0] >> 16;
        }
        #pragma unroll
        for (int h = 0; h < 4; ++h)
            #pragma unroll
            for (int j = 0; j < 2; ++j) {
                unsigned vL = j ? Vp[h][0] : shl[h];
                unsigned vR = j ? shr[h] : Vp[h][1];
                unsigned tU = (h > 0) ? pkfma(pp[h][j], Vp[h-1][j], aU2[h][j]) : aU2[h][j];
                unsigned tD = (h < 3) ? pkfma(pp[h][j], Vp[h+1][j], aD2[h][j]) : aD2[h][j];
                unsigned m1 = pkmax(Vp[h][j], pkfma(pp[h][j], vL, aL2[h][j]));
                unsigned m2 = pkmax(pkfma(pp[h][j], vR, aR2[h][j]), tU);
                Vn[h][j] = pkmax(pkmax(m1, m2), tD);
            }
        #pragma unroll
        for (int h = 0; h < 4; ++h) { Vp[h][0] = Vn[h][0]; Vp[h][1] = Vn[h][1]; }
    }

    // ---- unpack V, store to own row words 0..15 (+zero sentinel at word 16) ----
    {
        char* myrow = wbase + lane * 144;
        #pragma unroll
        for (int h = 0; h < 4; ++h) {
            h2 a = __builtin_bit_cast(h2, Vp[h][0]);
            h2 c = __builtin_bit_cast(h2, Vp[h][1]);
            *reinterpret_cast<f32x4*>(myrow + h * 16) =
                (f32x4){(float)a[0], (float)c[0], (float)a[1], (float)c[1]};
        }
        *reinterpret_cast<float*>(myrow + 64) = 0.0f;   // word 16: gather sentinel
    }
    asm volatile("s_waitcnt lgkmcnt(0)" ::: "memory");
    __builtin_amdgcn_sched_barrier(0);
    {
        const float* myv = reinterpret_cast<const float*>(wbase + lane * 144);
        #pragma unroll
        for (int dh = 0; dh < 3; ++dh)
            #pragma unroll
            for (int dw = 0; dw < 3; ++dw) {
                int r = ai + dh - 1, c = aj + dw - 1;
                bool ok = ((unsigned)r < 4u) && ((unsigned)c < 4u);
                int ba = ok ? (r*4 + c) : 16;   // 16 -> zero sentinel
                float v = myv[ba];
                int f = 27 + dh*3 + dw;
                lg0 = fmaf(v, LW[0*36+f], lg0);
                lg1 = fmaf(v, LW[1*36+f], lg1);
                lg2 = fmaf(v, LW[2*36+f], lg2);
                lg3 = fmaf(v, LW[3*36+f], lg3);
            }
    }

    reinterpret_cast<float4*>(out)[b] = make_float4(lg0, lg1, lg2, lg3);
}

extern "C" void kernel_launch(void* const* d_in, const int* in_sizes, int n_in,
                              void* d_out, int out_size, void* d_ws, size_t ws_size,
                              hipStream_t stream) {
    const float* obs  = (const float*)d_in[0];
    const float* PhiW = (const float*)d_in[1];
    const float* Phib = (const float*)d_in[2];
    const float* LW   = (const float*)d_in[3];
    const float* Lb   = (const float*)d_in[4];
    float* out = (float*)d_out;

    const int Btot = in_sizes[0] / 48;   // 1,000,000
    const int grid = (Btot + BT - 1) / BT;
    hipLaunchKernelGGL(vin_kernel, dim3(grid), dim3(BT), 0, stream,
                       obs, PhiW, Phib, LW, Lb, out, Btot);
}

// Round 10
// 68.336 us; speedup vs baseline: 1.0350x; 1.0350x over previous
//
#include <hip/hip_runtime.h>

#define BT 256           // 4 waves per block
#define WREG 9216        // per-wave LDS: 64 rows x 144 B (A-area; strip + V overlay it)
// A-row: 72 shorts = 48 bf16 obs + 16 zero K-pad (shorts 48..63; also gather sentinel)
// strip (post-MFMA, per column-tile): words 0..15 of each row, reused 3x
// V-area (post-VI): words 0..15 + zero sentinel word 16

// Compiler-only fence: orders memory ops across the type-punned LDS overlays.
// No HW wait needed: within-wave LDS ops issue AND complete in order.
#define MEMFENCE asm volatile("" ::: "memory")

typedef __attribute__((ext_vector_type(8))) short short8;
typedef __attribute__((ext_vector_type(4))) float f32x4;
typedef __attribute__((ext_vector_type(4))) unsigned int u32x4;
typedef _Float16 h2 __attribute__((ext_vector_type(2)));

__device__ inline unsigned cvtpkbf(float a, float b) {   // 2xf32 -> 2xbf16 (RNE)
    unsigned d;
    asm("v_cvt_pk_bf16_f32 %0, %1, %2" : "=v"(d) : "v"(a), "v"(b));
    return d;
}
__device__ inline float b2f(short s) {
    unsigned u = ((unsigned)(unsigned short)s) << 16;
    return __builtin_bit_cast(float, u);
}
__device__ inline unsigned pkrtz(float a, float b) {     // 2xf32 -> 2xf16 (RTZ)
    unsigned d;
    asm("v_cvt_pkrtz_f16_f32 %0, %1, %2" : "=v"(d) : "v"(a), "v"(b));
    return d;
}
__device__ inline unsigned pkfma(unsigned a, unsigned b, unsigned c) {
    unsigned d;
    asm("v_pk_fma_f16 %0, %1, %2, %3" : "=v"(d) : "v"(a), "v"(b), "v"(c));
    return d;
}
__device__ inline unsigned pkmax(unsigned a, unsigned b) {
    unsigned d;
    asm("v_pk_max_f16 %0, %1, %2" : "=v"(d) : "v"(a), "v"(b));
    return d;
}
__device__ inline unsigned pksub(unsigned a, unsigned b) {   // a - b
    unsigned d;
    asm("v_pk_add_f16 %0, %1, %2 neg_lo:[0,1] neg_hi:[0,1]" : "=v"(d) : "v"(a), "v"(b));
    return d;
}
__device__ inline unsigned pkneg(unsigned b) {               // -b
    unsigned d;
    asm("v_pk_add_f16 %0, 0, %1 neg_lo:[0,1] neg_hi:[0,1]" : "=v"(d) : "v"(b));
    return d;
}

// one VI step: D = step(S); pack (h,j): lo=V[h][j], hi=V[h][j+2]
__device__ inline void vistep(const unsigned (&S)[4][2], unsigned (&D)[4][2],
                              const unsigned (&pp)[4][2],
                              const unsigned (&aL)[4][2], const unsigned (&aR)[4][2],
                              const unsigned (&aU)[4][2], const unsigned (&aD)[4][2])
{
    unsigned shl[4], shr[4];
    #pragma unroll
    for (int h = 0; h < 4; ++h) {
        shl[h] = S[h][1] << 16;      // L-nb of (h,0): (bnd, V[h][1])
        shr[h] = S[h][0] >> 16;      // R-nb of (h,1): (V[h][2], bnd)
    }
    #pragma unroll
    for (int h = 0; h < 4; ++h)
        #pragma unroll
        for (int j = 0; j < 2; ++j) {
            unsigned vL = j ? S[h][0] : shl[h];
            unsigned vR = j ? shr[h] : S[h][1];
            unsigned tU = (h > 0) ? pkfma(pp[h][j], S[h-1][j], aU[h][j]) : aU[h][j];
            unsigned tD = (h < 3) ? pkfma(pp[h][j], S[h+1][j], aD[h][j]) : aD[h][j];
            unsigned m1 = pkmax(S[h][j], pkfma(pp[h][j], vL, aL[h][j]));
            unsigned m2 = pkmax(pkfma(pp[h][j], vR, aR[h][j]), tU);
            D[h][j] = pkmax(pkmax(m1, m2), tD);
        }
}

__global__ __launch_bounds__(BT, 4) void vin_kernel(
    const float* __restrict__ obs,
    const float* __restrict__ PhiW,
    const float* __restrict__ Phib,
    const float* __restrict__ LW,
    const float* __restrict__ Lb,
    float* __restrict__ out, int Btot)
{
    __shared__ __align__(16) char smem[4 * WREG];   // 36864 B -> 4 blocks/CU
    const int tid  = threadIdx.x;
    const int lane = tid & 63;
    const int wid  = tid >> 6;
    const int b    = blockIdx.x * BT + tid;
    // Btot % 64 == 0, waves entirely in or out; no barriers -> early return safe
    if (b >= Btot) return;

    char* wbase = smem + wid * WREG;
    const int jn = lane & 15;
    const int g  = lane >> 4;

    // ---- load obs row (48 f32, 12x float4, coalesced) ----
    float o[48];
    {
        const float4* g4 = reinterpret_cast<const float4*>(obs + (size_t)b * 48);
        #pragma unroll
        for (int q = 0; q < 12; ++q) {
            float4 t = g4[q];
            o[4*q+0] = t.x; o[4*q+1] = t.y; o[4*q+2] = t.z; o[4*q+3] = t.w;
        }
    }

    // ---- agent index: channel 1 is exactly one-hot (values exactly 1.0f) ----
    float sidx = 0.0f;
    #pragma unroll
    for (int k = 1; k < 16; ++k)
        sidx = fmaf(o[k*3 + 1], (float)k, sidx);
    const int idx = (int)(sidx + 0.5f);
    const int ai = idx >> 2;
    const int aj = idx & 3;

    // ---- B-fragments: PhiW^T tiles straight from global (L2-hot), bf16 ----
    // B[k][j] = PhiW[j*48+k]; lane holds col j=16n+jn, k = 32t+8g..+7
    short8 bfrag[3][2];
    #pragma unroll
    for (int n = 0; n < 3; ++n) {
        const float* wrow = PhiW + (16*n + jn) * 48;
        float4 q0 = *reinterpret_cast<const float4*>(wrow + 8*g);
        float4 q1 = *reinterpret_cast<const float4*>(wrow + 8*g + 4);
        u32x4 t0;
        t0[0] = cvtpkbf(q0.x, q0.y); t0[1] = cvtpkbf(q0.z, q0.w);
        t0[2] = cvtpkbf(q1.x, q1.y); t0[3] = cvtpkbf(q1.z, q1.w);
        bfrag[n][0] = __builtin_bit_cast(short8, t0);
        u32x4 tz = {0u, 0u, 0u, 0u};
        if (g < 2) {   // k = 32+8g..+7 valid only for g<2; k>=48 zero pad
            float4 q2 = *reinterpret_cast<const float4*>(wrow + 32 + 8*g);
            float4 q3 = *reinterpret_cast<const float4*>(wrow + 36 + 8*g);
            tz[0] = cvtpkbf(q2.x, q2.y); tz[1] = cvtpkbf(q2.z, q2.w);
            tz[2] = cvtpkbf(q3.x, q3.y); tz[3] = cvtpkbf(q3.z, q3.w);
        }
        bfrag[n][1] = __builtin_bit_cast(short8, tz);
    }

    // ---- write own obs row to A-area as bf16 (packed cvt), K-pad to 64 ----
    {
        u32x4* arow = reinterpret_cast<u32x4*>(wbase + lane * 144);
        #pragma unroll
        for (int q = 0; q < 6; ++q) {
            u32x4 v;
            #pragma unroll
            for (int e = 0; e < 4; ++e)
                v[e] = cvtpkbf(o[q*8 + 2*e], o[q*8 + 2*e + 1]);
            arow[q] = v;
        }
        u32x4 z = {0u, 0u, 0u, 0u};
        arow[6] = z; arow[7] = z;   // shorts 48..63 zero (K-pad + gather sentinel)
    }
    MEMFENCE;   // A-writes before gather reads (compiler order; HW is in-order)

    // ---- sub_state gather (features 0..26) from own bf16 row ----
    // OOB windows read the zero-pad at shorts 48..50 (sentinel) - no value masks.
    float lg0 = Lb[0], lg1 = Lb[1], lg2 = Lb[2], lg3 = Lb[3];
    {
        const short* myobs = reinterpret_cast<const short*>(wbase + lane * 144);
        #pragma unroll
        for (int dh = 0; dh < 3; ++dh)
            #pragma unroll
            for (int dw = 0; dw < 3; ++dw) {
                int r = ai + dh - 1, c = aj + dw - 1;
                bool ok = ((unsigned)r < 4u) && ((unsigned)c < 4u);
                int ba = ok ? (r*4 + c) * 3 : 48;
                float s0 = b2f(myobs[ba+0]);
                float s1 = b2f(myobs[ba+1]);
                float s2 = b2f(myobs[ba+2]);
                int f = (dh*3 + dw) * 3;
                lg0 = fmaf(s0, LW[0*36+f], fmaf(s1, LW[0*36+f+1], fmaf(s2, LW[0*36+f+2], lg0)));
                lg1 = fmaf(s0, LW[1*36+f], fmaf(s1, LW[1*36+f+1], fmaf(s2, LW[1*36+f+2], lg1)));
                lg2 = fmaf(s0, LW[2*36+f], fmaf(s1, LW[2*36+f+1], fmaf(s2, LW[2*36+f+2], lg2)));
                lg3 = fmaf(s0, LW[3*36+f], fmaf(s1, LW[3*36+f+1], fmaf(s2, LW[3*36+f+2], lg3)));
            }
    }

    // ---- A-fragments: lane reads row m*16+jn, k = 32t+8g..+7 ----
    short8 afrag[4][2];
    #pragma unroll
    for (int m = 0; m < 4; ++m) {
        const char* rp = wbase + (m*16 + jn) * 144;
        afrag[m][0] = *reinterpret_cast<const short8*>(rp + 16*g);
        afrag[m][1] = *reinterpret_cast<const short8*>(rp + 64 + 16*g);
    }
    MEMFENCE;   // afrag reads issued before strip writes (in-order DS -> WAR safe)

    // ---- per column-tile: 8 MFMAs -> scatter -> readback (acc lives 16 regs) ----
    float rinf[16], routf[16], pcf[16];
    const float bias[3] = {Phib[jn], Phib[16 + jn], Phib[32 + jn]};
    #pragma unroll
    for (int n = 0; n < 3; ++n) {
        f32x4 acc[4];
        #pragma unroll
        for (int m = 0; m < 4; ++m) {
            float bn = bias[n];
            acc[m] = (f32x4){bn, bn, bn, bn};
            acc[m] = __builtin_amdgcn_mfma_f32_16x16x32_bf16(afrag[m][0], bfrag[n][0], acc[m], 0, 0, 0);
            acc[m] = __builtin_amdgcn_mfma_f32_16x16x32_bf16(afrag[m][1], bfrag[n][1], acc[m], 0, 0, 0);
        }
        // scatter D: lane holds col 16n+jn, rows m*16+g*4+r
        #pragma unroll
        for (int m = 0; m < 4; ++m)
            #pragma unroll
            for (int r = 0; r < 4; ++r) {
                int row = m*16 + g*4 + r;
                reinterpret_cast<float*>(wbase + row * 144)[jn] = acc[m][r];
            }
        MEMFENCE;   // scatter writes before readback reads (RAW via in-order DS)
        // readback own row's 16 cols of this tile, route by col%3
        const char* myrow = wbase + lane * 144;
        #pragma unroll
        for (int q = 0; q < 4; ++q) {
            f32x4 t = *reinterpret_cast<const f32x4*>(myrow + q * 16);
            #pragma unroll
            for (int e = 0; e < 4; ++e) {
                int c = 16*n + 4*q + e;
                int cell = c / 3, ch = c - 3*cell;
                if (ch == 0)      rinf[cell]  = t[e];
                else if (ch == 1) routf[cell] = t[e];
                else              pcf[cell]   = t[e];
            }
        }
        MEMFENCE;   // readback reads before next tile's scatter writes (WAR)
    }

    // ---- pack rin/rout/p into f16 pairs (cl, cl+2), build a* in packed math ----
    unsigned rinp[4][2], routp[4][2], pp[4][2];
    #pragma unroll
    for (int h = 0; h < 4; ++h)
        #pragma unroll
        for (int j = 0; j < 2; ++j) {
            int c0 = 4*h + j, c1 = 4*h + j + 2;
            rinp[h][j]  = pkrtz(rinf[c0], rinf[c1]);
            routp[h][j] = pkrtz(routf[c0], routf[c1]);
            pp[h][j]    = pkrtz(pcf[c0], pcf[c1]);
        }
    unsigned aL2[4][2], aR2[4][2], aU2[4][2], aD2[4][2];
    #pragma unroll
    for (int h = 0; h < 4; ++h) {
        aL2[h][0] = pksub(rinp[h][1] << 16, routp[h][0]);
        aL2[h][1] = pksub(rinp[h][0], routp[h][1]);
        aR2[h][0] = pksub(rinp[h][1], routp[h][0]);
        aR2[h][1] = pksub(rinp[h][0] >> 16, routp[h][1]);
        #pragma unroll
        for (int j = 0; j < 2; ++j) {
            aU2[h][j] = (h > 0) ? pksub(rinp[h-1][j], routp[h][j]) : pkneg(routp[0][j]);
            aD2[h][j] = (h < 3) ? pksub(rinp[h+1][j], routp[h][j]) : pkneg(routp[3][j]);
        }
    }

    // ---- K=20 VI steps, packed f16, unrolled x2 (ping-pong, no copies) ----
    unsigned Vp[4][2], Vn[4][2];
    #pragma unroll
    for (int h = 0; h < 4; ++h) { Vp[h][0] = 0u; Vp[h][1] = 0u; }
    #pragma unroll 1
    for (int s = 0; s < 10; ++s) {
        vistep(Vp, Vn, pp, aL2, aR2, aU2, aD2);
        vistep(Vn, Vp, pp, aL2, aR2, aU2, aD2);
    }

    // ---- unpack V, store to own row words 0..15 (+zero sentinel at word 16) ----
    {
        char* myrow = wbase + lane * 144;
        #pragma unroll
        for (int h = 0; h < 4; ++h) {
            h2 a = __builtin_bit_cast(h2, Vp[h][0]);
            h2 c = __builtin_bit_cast(h2, Vp[h][1]);
            *reinterpret_cast<f32x4*>(myrow + h * 16) =
                (f32x4){(float)a[0], (float)c[0], (float)a[1], (float)c[1]};
        }
        *reinterpret_cast<float*>(myrow + 64) = 0.0f;   // word 16: gather sentinel
    }
    MEMFENCE;   // V writes before V gather reads (RAW via in-order DS)
    {
        const float* myv = reinterpret_cast<const float*>(wbase + lane * 144);
        #pragma unroll
        for (int dh = 0; dh < 3; ++dh)
            #pragma unroll
            for (int dw = 0; dw < 3; ++dw) {
                int r = ai + dh - 1, c = aj + dw - 1;
                bool ok = ((unsigned)r < 4u) && ((unsigned)c < 4u);
                int ba = ok ? (r*4 + c) : 16;   // 16 -> zero sentinel
                float v = myv[ba];
                int f = 27 + dh*3 + dw;
                lg0 = fmaf(v, LW[0*36+f], lg0);
                lg1 = fmaf(v, LW[1*36+f], lg1);
                lg2 = fmaf(v, LW[2*36+f], lg2);
                lg3 = fmaf(v, LW[3*36+f], lg3);
            }
    }

    reinterpret_cast<float4*>(out)[b] = make_float4(lg0, lg1, lg2, lg3);
}

extern "C" void kernel_launch(void* const* d_in, const int* in_sizes, int n_in,
                              void* d_out, int out_size, void* d_ws, size_t ws_size,
                              hipStream_t stream) {
    const float* obs  = (const float*)d_in[0];
    const float* PhiW = (const float*)d_in[1];
    const float* Phib = (const float*)d_in[2];
    const float* LW   = (const float*)d_in[3];
    const float* Lb   = (const float*)d_in[4];
    float* out = (float*)d_out;

    const int Btot = in_sizes[0] / 48;   // 1,000,000
    const int grid = (Btot + BT - 1) / BT;
    hipLaunchKernelGGL(vin_kernel, dim3(grid), dim3(BT), 0, stream,
                       obs, PhiW, Phib, LW, Lb, out, Btot);
}